// Round 3
// baseline (130.239 us; speedup 1.0000x reference)
//
#include <hip/hip_runtime.h>

#define B_  128
#define N_  16
#define T_  32
#define H_  128
#define NH_ 4
#define L_  544   // (N_+1)*T_
#define CH  64    // kv rows per chunk
#define NC  9     // ceil(544/64)

// ---------------- K1: qk[b][n][h] = w_ks[n]·(q[b]·w_qs[n]) ----------------
__global__ __launch_bounds__(256) void qk_kernel(
    const float* __restrict__ node_enc, const int* __restrict__ cts_p,
    const float* __restrict__ w_qs, const float* __restrict__ w_ks,
    float* __restrict__ qk_ws)
{
    const int blk = blockIdx.x;
    const int b = blk & 127, n = blk >> 7;
    const int t = threadIdx.x;
    __shared__ float q_sh[H_];
    __shared__ float ps[256];
    __shared__ float qs_sh[H_];

    if (t < H_) q_sh[t] = node_enc[(size_t)b*T_*H_ + cts_p[0]*H_ + t];
    __syncthreads();
    {   // q_s[d] = sum_h q[h]*w_qs[n][h][d]; 2 threads per d (h split)
        int d = t & 127, half = t >> 7;
        const float* w  = w_qs + (size_t)n*H_*H_ + (half*64)*H_ + d;
        const float* qh = q_sh + half*64;
        float acc = 0.f;
        #pragma unroll 8
        for (int h = 0; h < 64; ++h) acc += qh[h] * w[h*H_];
        ps[t] = acc;
    }
    __syncthreads();
    if (t < H_) qs_sh[t] = ps[t] + ps[t+128];
    __syncthreads();
    {   // qk[h] = sum_d w_ks[n][h][d]*q_s[d]; 2 threads per h (d split)
        int h = t & 127, half = t >> 7;
        const float4* w  = (const float4*)(w_ks + (size_t)n*H_*H_ + h*H_ + half*64);
        const float4* qs = (const float4*)(qs_sh + half*64);
        float acc = 0.f;
        #pragma unroll
        for (int i = 0; i < 16; ++i) {
            float4 wv = w[i], qv = qs[i];
            acc += wv.x*qv.x + wv.y*qv.y + wv.z*qv.z + wv.w*qv.w;
        }
        ps[t] = acc;
    }
    __syncthreads();
    if (t < H_) qk_ws[(b*NH_ + n)*H_ + t] = ps[t] + ps[t+128];
}

// ---- K2: single kv pass: scores + chunk-local softmax + partial wctx ----
// Stores P = exp(S - m_chunk) (unnormalized) and per-chunk (m, s) stats.
__global__ __launch_bounds__(256, 4) void attn_main_kernel(
    const float* __restrict__ node_enc, const float* __restrict__ neigh_enc,
    const int* __restrict__ attn_mask, const float* __restrict__ qk_ws,
    float* __restrict__ P_ws, float* __restrict__ wpart_ws,
    float* __restrict__ stats_ws)
{
    const int blk = blockIdx.x;
    const int b = blk / NC, c = blk % NC;
    const int t = threadIdx.x;
    const int l0 = c * CH;
    const int R  = min(CH, L_ - l0);   // 64, last chunk 32

    __shared__ __align__(16) float kv_sh[CH*132];  // +4 pad per row
    __shared__ __align__(16) float qk_sh[4*132];
    __shared__ float S_sh[CH*5];
    __shared__ float P_sh[CH*6];
    __shared__ int   msk_sh[CH];

    for (int j = t; j < 4*H_; j += 256) {
        int g = j >> 7, h = j & 127;
        qk_sh[g*132 + h] = qk_ws[(b*NH_ + g)*H_ + h];
    }
    if (t < R) msk_sh[t] = attn_mask[b*L_ + l0 + t];
    for (int j = t; j < R*32; j += 256) {
        int r = j >> 5, cc = j & 31;
        int l = l0 + r;
        const float* rowp = (l < T_)
            ? node_enc  + (size_t)b*T_*H_ + l*H_
            : neigh_enc + (size_t)b*N_*T_*H_ + (size_t)(l - T_)*H_;
        float4 v = ((const float4*)rowp)[cc];
        *((float4*)(kv_sh + r*132 + cc*4)) = v;
    }
    __syncthreads();

    // scores: thread (r,g), r=t>>2, g=t&3
    {
        int r = t >> 2, g = t & 3;
        float S = -INFINITY;
        if (r < R) {
            const float4* kvv = (const float4*)(kv_sh + r*132);
            const float4* qv  = (const float4*)(qk_sh + g*132);
            float acc = 0.f;
            #pragma unroll
            for (int i = 0; i < 32; ++i) {
                float4 a = kvv[i], q = qv[i];
                acc += a.x*q.x + a.y*q.y + a.z*q.z + a.w*q.w;
            }
            S = msk_sh[r] ? -INFINITY : acc * 0.08838834764831845f;
        }
        S_sh[r*5 + g] = S;
    }
    __syncthreads();

    // chunk-local softmax stats per head: wave w handles head w
    {
        int w = t >> 6, lane = t & 63;
        float v = S_sh[lane*5 + w];
        float m = v;
        #pragma unroll
        for (int off = 32; off > 0; off >>= 1) m = fmaxf(m, __shfl_xor(m, off, 64));
        m = fmaxf(m, -1e30f);                    // guard fully-masked chunk
        float p = __expf(v - m);                 // v=-inf -> 0
        P_sh[lane*6 + w] = p;
        float s = p;
        #pragma unroll
        for (int off = 32; off > 0; off >>= 1) s += __shfl_xor(s, off, 64);
        if (lane == 0) {
            stats_ws[((b*NC + c)*NH_ + w)*2 + 0] = m;
            stats_ws[((b*NC + c)*NH_ + w)*2 + 1] = s;
        }
    }
    __syncthreads();

    // coalesced P writeout (unnormalized probs; finish rescales)
    for (int j = t; j < R*NH_; j += 256) {
        int r = j >> 2, g = j & 3;
        P_ws[((size_t)b*L_ + l0 + r)*NH_ + g] = P_sh[r*6 + g];
    }

    // partial wctx from the SAME LDS kv copy (no 2nd HBM pass)
    {
        int h = t & 127, gp = t >> 7;   // gp=0 -> heads 0,1; gp=1 -> heads 2,3
        float acc0 = 0.f, acc1 = 0.f;
        #pragma unroll 4
        for (int r = 0; r < R; ++r) {
            float  kvv = kv_sh[r*132 + h];
            float2 p = *((const float2*)(P_sh + r*6 + gp*2));
            acc0 += p.x * kvv;
            acc1 += p.y * kvv;
        }
        float* wp = wpart_ws + (size_t)(b*NC + c)*NH_*H_;
        wp[(gp*2+0)*H_ + h] = acc0;
        wp[(gp*2+1)*H_ + h] = acc1;
    }
}

// ---- K3: grid 2*B. role 0: slf_attn. role 1: wctx->ctx->proj->LN ----
__global__ __launch_bounds__(512) void finish_kernel(
    const float* __restrict__ node_enc, const int* __restrict__ cts_p,
    const float* __restrict__ w_vs, const float* __restrict__ prj_w,
    const float* __restrict__ prj_b, const float* __restrict__ ln_gamma,
    const float* __restrict__ ln_beta, const float* __restrict__ P_ws,
    const float* __restrict__ wpart_ws, const float* __restrict__ stats_ws,
    float* __restrict__ d_out)
{
    const int b = blockIdx.x >> 1, role = blockIdx.x & 1;
    const int t = threadIdx.x;
    __shared__ float stats_sh[NC*NH_*2];
    __shared__ float m_sh[NH_], inv_sh[NH_];
    __shared__ float scale_sh[NC*NH_];

    if (t < NC*NH_*2) stats_sh[t] = stats_ws[b*NC*NH_*2 + t];
    __syncthreads();
    if (t < NH_) {
        float m = -INFINITY;
        #pragma unroll
        for (int c = 0; c < NC; ++c) m = fmaxf(m, stats_sh[(c*NH_+t)*2]);
        float s = 0.f;
        #pragma unroll
        for (int c = 0; c < NC; ++c)
            s += stats_sh[(c*NH_+t)*2+1] * __expf(stats_sh[(c*NH_+t)*2] - m);
        m_sh[t] = m;
        inv_sh[t] = 1.0f / s;
    }
    __syncthreads();
    if (t < NC*NH_) {
        int c = t >> 2, n = t & 3;
        scale_sh[t] = __expf(stats_sh[(c*NH_+n)*2] - m_sh[n]) * inv_sh[n];
    }
    __syncthreads();

    if (role == 0) {
        // slf_attn[b,0,l] = sum_n P[l][n] * scale[c(l)][n]
        float* slf = d_out + B_*H_ + b*L_;
        const float4* Pr = (const float4*)(P_ws + (size_t)b*L_*NH_);
        for (int l = t; l < L_; l += 512) {
            float4 p4 = Pr[l];
            const float* sc = scale_sh + (l >> 6)*NH_;
            slf[l] = p4.x*sc[0] + p4.y*sc[1] + p4.z*sc[2] + p4.w*sc[3];
        }
        return;
    }

    __shared__ __align__(16) float wctx_sh[NH_*H_];
    __shared__ __align__(16) float cat_sh[NH_*H_];
    __shared__ float rb_sh[H_];   // prj_b + residual
    __shared__ float x_sh[H_];
    __shared__ float st2[2];

    if (t < H_)
        rb_sh[t] = prj_b[t] + node_enc[(size_t)b*T_*H_ + cts_p[0]*H_ + t];
    // wctx: rescale-combine partials (512 values, 1/thread)
    {
        int n = t >> 7;
        const float* wp = wpart_ws + (size_t)b*NC*NH_*H_;
        float acc = 0.f;
        #pragma unroll
        for (int c = 0; c < NC; ++c)
            acc += wp[c*NH_*H_ + t] * scale_sh[c*NH_ + n];
        wctx_sh[t] = acc;
    }
    __syncthreads();
    // cat[n*128+d] = sum_h wctx[n][h]*w_vs[n][h][d]  (coalesced over d)
    {
        int n = t >> 7, d = t & 127;
        const float* w  = w_vs + (size_t)n*H_*H_ + d;
        const float* wc = wctx_sh + n*H_;
        float acc = 0.f;
        #pragma unroll 8
        for (int h = 0; h < H_; ++h) acc += wc[h] * w[h*H_];
        cat_sh[t] = acc;
    }
    __syncthreads();
    // proj: wave per output row j; lanes cover 8 consecutive c each (coalesced)
    {
        int w = t >> 6, lane = t & 63;
        float4 ca = *((const float4*)(cat_sh + lane*8));
        float4 cb = *((const float4*)(cat_sh + lane*8 + 4));
        #pragma unroll
        for (int i = 0; i < 16; ++i) {
            int j = w*16 + i;
            const float4* wr = (const float4*)(prj_w + (size_t)j*(NH_*H_) + lane*8);
            float4 w0 = wr[0], w1 = wr[1];
            float d = w0.x*ca.x + w0.y*ca.y + w0.z*ca.z + w0.w*ca.w
                    + w1.x*cb.x + w1.y*cb.y + w1.z*cb.z + w1.w*cb.w;
            #pragma unroll
            for (int off = 32; off > 0; off >>= 1) d += __shfl_xor(d, off, 64);
            if (lane == 0) x_sh[j] = d + rb_sh[j];
        }
    }
    __syncthreads();
    if (t < 64) {
        float v0 = x_sh[t], v1 = x_sh[t+64];
        float s1 = v0 + v1, s2 = v0*v0 + v1*v1;
        #pragma unroll
        for (int off = 32; off > 0; off >>= 1) {
            s1 += __shfl_xor(s1, off, 64);
            s2 += __shfl_xor(s2, off, 64);
        }
        if (t == 0) {
            float mean = s1 / (float)H_;
            float var  = s2 / (float)H_ - mean*mean;
            st2[0] = mean;
            st2[1] = rsqrtf(var + 1e-6f);
        }
    }
    __syncthreads();
    if (t < H_)
        d_out[b*H_ + t] = (x_sh[t] - st2[0]) * st2[1] * ln_gamma[t] + ln_beta[t];
}

extern "C" void kernel_launch(void* const* d_in, const int* in_sizes, int n_in,
                              void* d_out, int out_size, void* d_ws, size_t ws_size,
                              hipStream_t stream) {
    const float* node_enc  = (const float*)d_in[0];
    const float* neigh_enc = (const float*)d_in[1];
    const int*   attn_mask = (const int*)d_in[2];
    const int*   cts       = (const int*)d_in[3];
    const float* w_qs      = (const float*)d_in[4];
    const float* w_ks      = (const float*)d_in[5];
    const float* w_vs      = (const float*)d_in[6];
    const float* prj_w     = (const float*)d_in[7];
    const float* prj_b     = (const float*)d_in[8];
    const float* ln_gamma  = (const float*)d_in[9];
    const float* ln_beta   = (const float*)d_in[10];

    float* qk_ws    = (float*)d_ws;                       // B*NH*H
    float* P_ws     = qk_ws + (size_t)B_*NH_*H_;          // B*L*NH
    float* wpart_ws = P_ws + (size_t)B_*L_*NH_;           // B*NC*NH*H
    float* stats_ws = wpart_ws + (size_t)B_*NC*NH_*H_;    // B*NC*NH*2

    qk_kernel<<<B_*NH_, 256, 0, stream>>>(node_enc, cts, w_qs, w_ks, qk_ws);
    attn_main_kernel<<<B_*NC, 256, 0, stream>>>(node_enc, neigh_enc, attn_mask,
                                                qk_ws, P_ws, wpart_ws, stats_ws);
    finish_kernel<<<B_*2, 512, 0, stream>>>(node_enc, cts, w_vs, prj_w, prj_b,
                                            ln_gamma, ln_beta, P_ws, wpart_ws,
                                            stats_ws, (float*)d_out);
}

// Round 4
// 128.320 us; speedup vs baseline: 1.0150x; 1.0150x over previous
//
#include <hip/hip_runtime.h>

#define B_  128
#define N_  16
#define T_  32
#define H_  128
#define NH_ 4
#define L_  544   // (N_+1)*T_
#define CH  32    // kv rows per chunk (544 = 17*32 exactly)
#define NC  17
#define KVP 132   // kv LDS row stride (+4 pad: rows -> banks 4r, 2-way max = free)

// ---------------- K1: qk[b][n][h] = w_ks[n]·(q[b]·w_qs[n]) ----------------
__global__ __launch_bounds__(256) void qk_kernel(
    const float* __restrict__ node_enc, const int* __restrict__ cts_p,
    const float* __restrict__ w_qs, const float* __restrict__ w_ks,
    float* __restrict__ qk_ws)
{
    const int blk = blockIdx.x;
    const int b = blk & 127, n = blk >> 7;
    const int t = threadIdx.x;
    __shared__ float q_sh[H_];
    __shared__ float ps[256];
    __shared__ float qs_sh[H_];

    if (t < H_) q_sh[t] = node_enc[(size_t)b*T_*H_ + cts_p[0]*H_ + t];
    __syncthreads();
    {   // q_s[d] = sum_h q[h]*w_qs[n][h][d]; 2 threads per d (h split)
        int d = t & 127, half = t >> 7;
        const float* w  = w_qs + (size_t)n*H_*H_ + (half*64)*H_ + d;
        const float* qh = q_sh + half*64;
        float acc = 0.f;
        #pragma unroll 8
        for (int h = 0; h < 64; ++h) acc += qh[h] * w[h*H_];
        ps[t] = acc;
    }
    __syncthreads();
    if (t < H_) qs_sh[t] = ps[t] + ps[t+128];
    __syncthreads();
    {   // qk[h] = sum_d w_ks[n][h][d]*q_s[d]; 2 threads per h (d split)
        int h = t & 127, half = t >> 7;
        const float4* w  = (const float4*)(w_ks + (size_t)n*H_*H_ + h*H_ + half*64);
        const float4* qs = (const float4*)(qs_sh + half*64);
        float acc = 0.f;
        #pragma unroll
        for (int i = 0; i < 16; ++i) {
            float4 wv = w[i], qv = qs[i];
            acc += wv.x*qv.x + wv.y*qv.y + wv.z*qv.z + wv.w*qv.w;
        }
        ps[t] = acc;
    }
    __syncthreads();
    if (t < H_) qk_ws[(b*NH_ + n)*H_ + t] = ps[t] + ps[t+128];
}

// ---- K2: single kv pass: scores + chunk-local softmax + partial wctx ----
// CH=32: LDS ~20.6 KB -> 7 blocks/CU; grid 2176 (8.5 blocks/CU).
__global__ __launch_bounds__(256, 4) void attn_main_kernel(
    const float* __restrict__ node_enc, const float* __restrict__ neigh_enc,
    const int* __restrict__ attn_mask, const float* __restrict__ qk_ws,
    float* __restrict__ P_ws, float* __restrict__ wpart_ws,
    float* __restrict__ stats_ws)
{
    const int blk = blockIdx.x;
    const int b = blk / NC, c = blk % NC;
    const int t = threadIdx.x;
    const int l0 = c * CH;

    __shared__ __align__(16) float kv_sh[CH*KVP];
    __shared__ __align__(16) float qk_sh[NH_*KVP];
    __shared__ float S_sh[CH*5];
    __shared__ float P_sh[CH*6];
    __shared__ int   msk_sh[CH];

    // chunk 0 is entirely node rows; chunks 1..16 entirely neigh rows
    const float* basep = (c == 0)
        ? node_enc  + (size_t)b*T_*H_
        : neigh_enc + (size_t)b*N_*T_*H_ + (size_t)(l0 - T_)*H_;

    for (int j = t; j < NH_*H_; j += 256) {
        int g = j >> 7, h = j & 127;
        qk_sh[g*KVP + h] = qk_ws[(b*NH_ + g)*H_ + h];
    }
    if (t < CH) msk_sh[t] = attn_mask[b*L_ + l0 + t];
    #pragma unroll
    for (int j = t; j < CH*32; j += 256) {
        int r = j >> 5, cc = j & 31;
        float4 v = ((const float4*)(basep + (size_t)r*H_))[cc];
        *((float4*)(kv_sh + r*KVP + cc*4)) = v;
    }
    __syncthreads();

    // scores: thread (r, g, half): r=t>>3, g=(t>>1)&3, half=t&1
    {
        int r = t >> 3, g = (t >> 1) & 3, half = t & 1;
        const float4* kvv = (const float4*)(kv_sh + r*KVP + half*64);
        const float4* qv  = (const float4*)(qk_sh + g*KVP + half*64);
        float acc = 0.f;
        #pragma unroll
        for (int i = 0; i < 16; ++i) {
            float4 a = kvv[i], q = qv[i];
            acc += a.x*q.x + a.y*q.y + a.z*q.z + a.w*q.w;
        }
        acc += __shfl_xor(acc, 1, 64);   // combine the two halves
        if (half == 0)
            S_sh[r*5 + g] = msk_sh[r] ? -INFINITY : acc * 0.08838834764831845f;
    }
    __syncthreads();

    // chunk-local softmax stats per head: wave w handles head w (32 rows)
    {
        int w = t >> 6, lane = t & 63;
        float v = (lane < CH) ? S_sh[lane*5 + w] : -INFINITY;
        float m = v;
        #pragma unroll
        for (int off = 32; off > 0; off >>= 1) m = fmaxf(m, __shfl_xor(m, off, 64));
        m = fmaxf(m, -1e30f);                    // guard fully-masked chunk
        float p = __expf(v - m);                 // -inf -> 0
        if (lane < CH) P_sh[lane*6 + w] = p;
        float s = p;
        #pragma unroll
        for (int off = 32; off > 0; off >>= 1) s += __shfl_xor(s, off, 64);
        if (lane == 0) {
            stats_ws[((b*NC + c)*NH_ + w)*2 + 0] = m;
            stats_ws[((b*NC + c)*NH_ + w)*2 + 1] = s;
        }
    }
    __syncthreads();

    // coalesced P writeout (unnormalized; finish rescales)
    if (t < CH*NH_) {
        int r = t >> 2, g = t & 3;
        P_ws[((size_t)b*L_ + l0 + r)*NH_ + g] = P_sh[r*6 + g];
    }

    // partial wctx from the SAME LDS kv copy (no 2nd HBM pass)
    {
        int h = t & 127, gp = t >> 7;   // gp=0 -> heads 0,1; gp=1 -> heads 2,3
        float acc0 = 0.f, acc1 = 0.f;
        #pragma unroll 4
        for (int r = 0; r < CH; ++r) {
            float  kvv = kv_sh[r*KVP + h];
            float2 p = *((const float2*)(P_sh + r*6 + gp*2));
            acc0 += p.x * kvv;
            acc1 += p.y * kvv;
        }
        float* wp = wpart_ws + (size_t)(b*NC + c)*NH_*H_;
        wp[(gp*2+0)*H_ + h] = acc0;
        wp[(gp*2+1)*H_ + h] = acc1;
    }
}

// ---- K3: grid 2*B. role 0: slf_attn. role 1: wctx->ctx->proj->LN ----
__global__ __launch_bounds__(512) void finish_kernel(
    const float* __restrict__ node_enc, const int* __restrict__ cts_p,
    const float* __restrict__ w_vs, const float* __restrict__ prj_w,
    const float* __restrict__ prj_b, const float* __restrict__ ln_gamma,
    const float* __restrict__ ln_beta, const float* __restrict__ P_ws,
    const float* __restrict__ wpart_ws, const float* __restrict__ stats_ws,
    float* __restrict__ d_out)
{
    const int b = blockIdx.x >> 1, role = blockIdx.x & 1;
    const int t = threadIdx.x;
    __shared__ float stats_sh[NC*NH_*2];
    __shared__ float m_sh[NH_], inv_sh[NH_];
    __shared__ float scale_sh[NC*NH_];

    if (t < NC*NH_*2) stats_sh[t] = stats_ws[b*NC*NH_*2 + t];
    __syncthreads();
    if (t < NH_) {
        float m = -INFINITY;
        #pragma unroll
        for (int c = 0; c < NC; ++c) m = fmaxf(m, stats_sh[(c*NH_+t)*2]);
        float s = 0.f;
        #pragma unroll
        for (int c = 0; c < NC; ++c)
            s += stats_sh[(c*NH_+t)*2+1] * __expf(stats_sh[(c*NH_+t)*2] - m);
        m_sh[t] = m;
        inv_sh[t] = 1.0f / s;
    }
    __syncthreads();
    if (t < NC*NH_) {
        int c = t >> 2, n = t & 3;
        scale_sh[t] = __expf(stats_sh[(c*NH_+n)*2] - m_sh[n]) * inv_sh[n];
    }
    __syncthreads();

    if (role == 0) {
        // slf_attn[b,0,l] = sum_n P[l][n] * scale[c(l)][n]
        float* slf = d_out + B_*H_ + b*L_;
        const float4* Pr = (const float4*)(P_ws + (size_t)b*L_*NH_);
        for (int l = t; l < L_; l += 512) {
            float4 p4 = Pr[l];
            const float* sc = scale_sh + (l >> 5)*NH_;
            slf[l] = p4.x*sc[0] + p4.y*sc[1] + p4.z*sc[2] + p4.w*sc[3];
        }
        return;
    }

    __shared__ __align__(16) float wctx_sh[NH_*H_];
    __shared__ __align__(16) float cat_sh[NH_*H_];
    __shared__ float rb_sh[H_];   // prj_b + residual
    __shared__ float x_sh[H_];
    __shared__ float st2[2];

    if (t < H_)
        rb_sh[t] = prj_b[t] + node_enc[(size_t)b*T_*H_ + cts_p[0]*H_ + t];
    // wctx: rescale-combine partials (512 values, 1/thread)
    {
        int n = t >> 7;
        const float* wp = wpart_ws + (size_t)b*NC*NH_*H_;
        float acc = 0.f;
        #pragma unroll
        for (int c = 0; c < NC; ++c)
            acc += wp[c*NH_*H_ + t] * scale_sh[c*NH_ + n];
        wctx_sh[t] = acc;
    }
    __syncthreads();
    // cat[n*128+d] = sum_h wctx[n][h]*w_vs[n][h][d]  (coalesced over d)
    {
        int n = t >> 7, d = t & 127;
        const float* w  = w_vs + (size_t)n*H_*H_ + d;
        const float* wc = wctx_sh + n*H_;
        float acc = 0.f;
        #pragma unroll 8
        for (int h = 0; h < H_; ++h) acc += wc[h] * w[h*H_];
        cat_sh[t] = acc;
    }
    __syncthreads();
    // proj: wave per output row j; lanes cover 8 consecutive c each (coalesced)
    {
        int w = t >> 6, lane = t & 63;
        float4 ca = *((const float4*)(cat_sh + lane*8));
        float4 cb = *((const float4*)(cat_sh + lane*8 + 4));
        #pragma unroll
        for (int i = 0; i < 16; ++i) {
            int j = w*16 + i;
            const float4* wr = (const float4*)(prj_w + (size_t)j*(NH_*H_) + lane*8);
            float4 w0 = wr[0], w1 = wr[1];
            float d = w0.x*ca.x + w0.y*ca.y + w0.z*ca.z + w0.w*ca.w
                    + w1.x*cb.x + w1.y*cb.y + w1.z*cb.z + w1.w*cb.w;
            #pragma unroll
            for (int off = 32; off > 0; off >>= 1) d += __shfl_xor(d, off, 64);
            if (lane == 0) x_sh[j] = d + rb_sh[j];
        }
    }
    __syncthreads();
    if (t < 64) {
        float v0 = x_sh[t], v1 = x_sh[t+64];
        float s1 = v0 + v1, s2 = v0*v0 + v1*v1;
        #pragma unroll
        for (int off = 32; off > 0; off >>= 1) {
            s1 += __shfl_xor(s1, off, 64);
            s2 += __shfl_xor(s2, off, 64);
        }
        if (t == 0) {
            float mean = s1 / (float)H_;
            float var  = s2 / (float)H_ - mean*mean;
            st2[0] = mean;
            st2[1] = rsqrtf(var + 1e-6f);
        }
    }
    __syncthreads();
    if (t < H_)
        d_out[b*H_ + t] = (x_sh[t] - st2[0]) * st2[1] * ln_gamma[t] + ln_beta[t];
}

extern "C" void kernel_launch(void* const* d_in, const int* in_sizes, int n_in,
                              void* d_out, int out_size, void* d_ws, size_t ws_size,
                              hipStream_t stream) {
    const float* node_enc  = (const float*)d_in[0];
    const float* neigh_enc = (const float*)d_in[1];
    const int*   attn_mask = (const int*)d_in[2];
    const int*   cts       = (const int*)d_in[3];
    const float* w_qs      = (const float*)d_in[4];
    const float* w_ks      = (const float*)d_in[5];
    const float* w_vs      = (const float*)d_in[6];
    const float* prj_w     = (const float*)d_in[7];
    const float* prj_b     = (const float*)d_in[8];
    const float* ln_gamma  = (const float*)d_in[9];
    const float* ln_beta   = (const float*)d_in[10];

    float* qk_ws    = (float*)d_ws;                       // B*NH*H
    float* P_ws     = qk_ws + (size_t)B_*NH_*H_;          // B*L*NH
    float* wpart_ws = P_ws + (size_t)B_*L_*NH_;           // B*NC*NH*H
    float* stats_ws = wpart_ws + (size_t)B_*NC*NH_*H_;    // B*NC*NH*2

    qk_kernel<<<B_*NH_, 256, 0, stream>>>(node_enc, cts, w_qs, w_ks, qk_ws);
    attn_main_kernel<<<B_*NC, 256, 0, stream>>>(node_enc, neigh_enc, attn_mask,
                                                qk_ws, P_ws, wpart_ws, stats_ws);
    finish_kernel<<<B_*2, 512, 0, stream>>>(node_enc, cts, w_vs, prj_w, prj_b,
                                            ln_gamma, ln_beta, P_ws, wpart_ws,
                                            stats_ws, (float*)d_out);
}